// Round 15
// baseline (206.585 us; speedup 1.0000x reference)
//
#include <hip/hip_runtime.h>
#include <hip/hip_bf16.h>

#define IN_DIM 256
#define NHEADS 8
#define HDIM 32
#define BATCH 2
#define NTOK 4096
#define QSCALE (0.17677669529663687f * 1.4426950408889634f)

typedef __hip_bfloat16 bf16;
typedef __attribute__((ext_vector_type(8))) short bf16x8;
typedef __attribute__((ext_vector_type(4))) short bf16x4;
typedef __attribute__((ext_vector_type(4))) float f32x4;

union bfrag { bf16x8 v; bf16x4 h[2]; };

__device__ __forceinline__ float b2f(bf16 x) { return __bfloat162float(x); }

#if __has_builtin(__builtin_amdgcn_exp2f)
__device__ __forceinline__ float fast_exp2(float x) { return __builtin_amdgcn_exp2f(x); }
#else
__device__ __forceinline__ float fast_exp2(float x) { return exp2f(x); }
#endif

__device__ __forceinline__ unsigned packbf2(float a, float b) {
    union { __hip_bfloat162 h; unsigned u; } c;
    c.h = __float22bfloat162_rn(float2{a, b});
    return c.u;
}

// pack 16 fp32 -> 16 bf16 into LDS (8B-aligned), as 4 uint2 writes
__device__ __forceinline__ void pack16(float4 a, float4 b, float4 c, float4 d,
                                       bf16* dst) {
    uint2 w0 = {packbf2(a.x, a.y), packbf2(a.z, a.w)};
    uint2 w1 = {packbf2(b.x, b.y), packbf2(b.z, b.w)};
    uint2 w2 = {packbf2(c.x, c.y), packbf2(c.z, c.w)};
    uint2 w3 = {packbf2(d.x, d.y), packbf2(d.z, d.w)};
    *(uint2*)(dst + 0)  = w0;
    *(uint2*)(dst + 4)  = w1;
    *(uint2*)(dst + 8)  = w2;
    *(uint2*)(dst + 12) = w3;
}

// ---------------------------------------------------------------------------
// Kernel A: MFMA QKV projection.  y[b][n][d] = sum_c X[b][c][n] * W[d][c]
// Q pre-scaled by QSCALE; V stored transposed Vt[b][d][n].
// grid (256, 3, 2); block 256 (4 waves).
// ---------------------------------------------------------------------------
__global__ __launch_bounds__(256) void proj_mfma(
    const float* __restrict__ tgt, const float* __restrict__ src,
    const float* __restrict__ Wq, const float* __restrict__ Wk,
    const float* __restrict__ Wv,
    bf16* __restrict__ Qo, bf16* __restrict__ Ko, bf16* __restrict__ Vo)
{
    const int which = blockIdx.y;
    const int dh = blockIdx.z;
    const int b  = blockIdx.x >> 7;
    const int n0 = (blockIdx.x & 127) * 32;
    const float* X = (which == 0) ? tgt : src;
    const float* W = (which == 0) ? Wq : (which == 1 ? Wk : Wv);

    const int tid = threadIdx.x;
    const int wave = tid >> 6, lane = tid & 63;
    const int lg = lane >> 4, lc = lane & 15;
    const int wn = wave & 1, wdq = wave >> 1;

    __shared__ bf16 As[32 * 260];              // [n][c], stride 260
    __shared__ bf16 Ws[2][128 * 36];           // [d][c-step], stride 36

    {
        const float* Xb = X + (size_t)b * IN_DIM * NTOK + n0;
        for (int it = 0; it < 8; ++it) {
            int idx = it * 256 + tid;
            int c = idx >> 3, j4 = idx & 7;
            float4 x = *(const float4*)(Xb + (size_t)c * NTOK + j4 * 4);
            As[(j4 * 4 + 0) * 260 + c] = __float2bfloat16(x.x);
            As[(j4 * 4 + 1) * 260 + c] = __float2bfloat16(x.y);
            As[(j4 * 4 + 2) * 260 + c] = __float2bfloat16(x.z);
            As[(j4 * 4 + 3) * 260 + c] = __float2bfloat16(x.w);
        }
    }
    const int wd = tid >> 1, wc = (tid & 1) * 16;
    const float* Wbase = W + (size_t)(dh * 128 + wd) * IN_DIM + wc;
    {
        float4 a = *(const float4*)(Wbase + 0);
        float4 bb = *(const float4*)(Wbase + 4);
        float4 cc = *(const float4*)(Wbase + 8);
        float4 dd = *(const float4*)(Wbase + 12);
        pack16(a, bb, cc, dd, &Ws[0][wd * 36 + wc]);
    }
    __syncthreads();

    f32x4 acc[4];
    #pragma unroll
    for (int t = 0; t < 4; ++t) acc[t] = f32x4{0.f, 0.f, 0.f, 0.f};

    for (int s = 0; s < 8; ++s) {
        const int c0 = s * 32;
        float4 pa, pb, pc, pd;
        if (s < 7) {
            const float* wn_ = Wbase + (s + 1) * 32;
            pa = *(const float4*)(wn_ + 0);
            pb = *(const float4*)(wn_ + 4);
            pc = *(const float4*)(wn_ + 8);
            pd = *(const float4*)(wn_ + 12);
        }
        bfrag af;
        const bf16* ap = &As[(wn * 16 + lc) * 260 + c0 + lg * 8];
        af.h[0] = *(const bf16x4*)ap;
        af.h[1] = *(const bf16x4*)(ap + 4);
        #pragma unroll
        for (int t = 0; t < 4; ++t) {
            bfrag wf;
            const bf16* wp = &Ws[s & 1][(wdq * 64 + t * 16 + lc) * 36 + lg * 8];
            wf.h[0] = *(const bf16x4*)wp;
            wf.h[1] = *(const bf16x4*)(wp + 4);
            acc[t] = __builtin_amdgcn_mfma_f32_16x16x32_bf16(af.v, wf.v, acc[t], 0, 0, 0);
        }
        if (s < 7) {
            __syncthreads();
            pack16(pa, pb, pc, pd, &Ws[(s + 1) & 1][wd * 36 + wc]);
            __syncthreads();
        }
    }

    const int nb = n0 + wn * 16 + lg * 4;
    if (which == 2) {
        #pragma unroll
        for (int t = 0; t < 4; ++t) {
            int d = dh * 128 + wdq * 64 + t * 16 + lc;
            uint2 pk;
            pk.x = packbf2(acc[t][0], acc[t][1]);
            pk.y = packbf2(acc[t][2], acc[t][3]);
            *(uint2*)(Vo + ((size_t)b * IN_DIM + d) * NTOK + nb) = pk;
        }
    } else {
        const float sc = (which == 0) ? QSCALE : 1.0f;
        bf16* O = (which == 0) ? Qo : Ko;
        #pragma unroll
        for (int t = 0; t < 4; ++t)
            #pragma unroll
            for (int r = 0; r < 4; ++r)
                O[((size_t)b * NTOK + nb + r) * IN_DIM + dh * 128 + wdq * 64 + t * 16 + lc]
                    = __float2bfloat16(acc[t][r] * sc);
    }
}

// ---------------------------------------------------------------------------
// Kernel B: MFMA flash attention — barrier-free, LDS-free.
//   - K/V MFMA fragments read DIRECTLY from global (L2-resident via XCD
//     swizzle); 1-tile register prefetch, x2-unrolled A/B register sets
//   - swapped QK^T: lane holds S[kv=t*16+lg*4+r][q=lc]
//   - PV + l as K=32 MFMAs via slot-merge: A = [P(t),P(t+1)] (16 cvt_pk),
//     B = [V(t),V(t+1)] (two b64 globals); ones8 column computes l
//   - no-max softmax via raw v_exp_f32; zero __syncthreads, zero LDS
// grid 512 (XCD-swizzled); block 256 (4 independent waves x 32 q).
// ---------------------------------------------------------------------------
__global__ __launch_bounds__(256) void attn_mfma_kernel(
    const bf16* __restrict__ Q, const bf16* __restrict__ K,
    const bf16* __restrict__ Vt, const float* __restrict__ tgt,
    bf16* __restrict__ Wt)
{
    const int blk = blockIdx.x;
    const int bh  = 2 * (blk & 7) + ((blk >> 3) & 1);
    const int qb  = blk >> 4;               // 0..31
    const int b = bh >> 3, h = bh & 7;
    const int tid  = threadIdx.x;
    const int wave = tid >> 6;
    const int lane = tid & 63;
    const int lg = lane >> 4, lc = lane & 15;
    const int qw = qb * 128 + wave * 32;

    const bf16x8 qfa = *(const bf16x8*)(Q + ((size_t)b * NTOK + qw + lc) * IN_DIM
                                          + h * HDIM + lg * 8);
    const bf16x8 qfb = *(const bf16x8*)(Q + ((size_t)b * NTOK + qw + 16 + lc) * IN_DIM
                                          + h * HDIM + lg * 8);

    bf16x8 ones8;
    #pragma unroll
    for (int i = 0; i < 8; ++i) ((short*)&ones8)[i] = (short)0x3F80;
    const f32x4 z = {0.f, 0.f, 0.f, 0.f};

    // fragment base pointers (per-lane)
    const bf16* Kr = K  + ((size_t)b * NTOK + lc) * IN_DIM + h * HDIM + lg * 8;
    const bf16* V0 = Vt + ((size_t)b * IN_DIM + h * HDIM + lc) * NTOK + lg * 4;
    const bf16* V1 = V0 + (size_t)16 * NTOK;

    f32x4 o0a = {0.f,0.f,0.f,0.f}, o1a = {0.f,0.f,0.f,0.f}, ola = {0.f,0.f,0.f,0.f};
    f32x4 o0b = {0.f,0.f,0.f,0.f}, o1b = {0.f,0.f,0.f,0.f}, olb = {0.f,0.f,0.f,0.f};

    bf16x8 kA[4], kB[4];
    bf16x4 vA0[4], vA1[4], vB0[4], vB1[4];   // [tcp*2 + pairhalf]

    const bf16* Kp = Kr;
    const bf16* V0p = V0;
    const bf16* V1p = V1;

#define LOADSET(KS, VS0, VS1)                                                  \
    {                                                                          \
        _Pragma("unroll")                                                      \
        for (int t = 0; t < 4; ++t)                                            \
            KS[t] = *(const bf16x8*)(Kp + (size_t)(t * 16) * IN_DIM);          \
        _Pragma("unroll")                                                      \
        for (int m = 0; m < 4; ++m) {                                          \
            VS0[m] = *(const bf16x4*)(V0p + m * 16);                           \
            VS1[m] = *(const bf16x4*)(V1p + m * 16);                           \
        }                                                                      \
        Kp  += (size_t)64 * IN_DIM;                                            \
        V0p += 64;                                                             \
        V1p += 64;                                                             \
    }

#define COMPUTE(KS, VS0, VS1)                                                  \
    {                                                                          \
        f32x4 sa[4], sb[4];                                                    \
        __builtin_amdgcn_s_setprio(1);                                         \
        _Pragma("unroll")                                                      \
        for (int t = 0; t < 4; ++t) {                                          \
            sa[t] = __builtin_amdgcn_mfma_f32_16x16x32_bf16(KS[t], qfa, z, 0,0,0); \
            sb[t] = __builtin_amdgcn_mfma_f32_16x16x32_bf16(KS[t], qfb, z, 0,0,0); \
        }                                                                      \
        __builtin_amdgcn_s_setprio(0);                                         \
        _Pragma("unroll")                                                      \
        for (int tcp = 0; tcp < 2; ++tcp) {                                    \
            union { bf16x8 v; uint4 u; } pa, pb;                               \
            pa.u.x = packbf2(fast_exp2(sa[2*tcp][0]), fast_exp2(sa[2*tcp][1]));     \
            pa.u.y = packbf2(fast_exp2(sa[2*tcp][2]), fast_exp2(sa[2*tcp][3]));     \
            pa.u.z = packbf2(fast_exp2(sa[2*tcp+1][0]), fast_exp2(sa[2*tcp+1][1])); \
            pa.u.w = packbf2(fast_exp2(sa[2*tcp+1][2]), fast_exp2(sa[2*tcp+1][3])); \
            pb.u.x = packbf2(fast_exp2(sb[2*tcp][0]), fast_exp2(sb[2*tcp][1]));     \
            pb.u.y = packbf2(fast_exp2(sb[2*tcp][2]), fast_exp2(sb[2*tcp][3]));     \
            pb.u.z = packbf2(fast_exp2(sb[2*tcp+1][0]), fast_exp2(sb[2*tcp+1][1])); \
            pb.u.w = packbf2(fast_exp2(sb[2*tcp+1][2]), fast_exp2(sb[2*tcp+1][3])); \
            bfrag B0, B1;                                                      \
            B0.h[0] = VS0[2*tcp]; B0.h[1] = VS0[2*tcp+1];                      \
            B1.h[0] = VS1[2*tcp]; B1.h[1] = VS1[2*tcp+1];                      \
            __builtin_amdgcn_s_setprio(1);                                     \
            o0a = __builtin_amdgcn_mfma_f32_16x16x32_bf16(pa.v, B0.v, o0a, 0,0,0); \
            o1a = __builtin_amdgcn_mfma_f32_16x16x32_bf16(pa.v, B1.v, o1a, 0,0,0); \
            ola = __builtin_amdgcn_mfma_f32_16x16x32_bf16(pa.v, ones8, ola, 0,0,0); \
            o0b = __builtin_amdgcn_mfma_f32_16x16x32_bf16(pb.v, B0.v, o0b, 0,0,0); \
            o1b = __builtin_amdgcn_mfma_f32_16x16x32_bf16(pb.v, B1.v, o1b, 0,0,0); \
            olb = __builtin_amdgcn_mfma_f32_16x16x32_bf16(pb.v, ones8, olb, 0,0,0); \
            __builtin_amdgcn_s_setprio(0);                                     \
        }                                                                      \
    }

    LOADSET(kA, vA0, vA1)                    // kt = 0
    for (int it = 0; it < NTOK / 128; ++it) {
        LOADSET(kB, vB0, vB1)                // prefetch kt+64 (last overruns ws: safe)
        COMPUTE(kA, vA0, vA1)
        LOADSET(kA, vA0, vA1)                // prefetch kt+128
        COMPUTE(kB, vB0, vB1)
    }
#undef LOADSET
#undef COMPUTE

    // ---- epilogue: divide by l (D layout), add residual, store both q-tiles
    const float* tga = tgt + ((size_t)b * IN_DIM + h * HDIM + lc) * NTOK + qw + lg * 4;
    float4 r0a = *(const float4*)tga;
    float4 r1a = *(const float4*)(tga + (size_t)16 * NTOK);
    float4 r0b = *(const float4*)(tga + 16);
    float4 r1b = *(const float4*)(tga + (size_t)16 * NTOK + 16);

    bf16* opa = Wt + ((size_t)b * NTOK + qw + lg * 4) * IN_DIM + h * HDIM + lc;
    bf16* opb = opa + (size_t)16 * IN_DIM;
    #pragma unroll
    for (int r = 0; r < 4; ++r) {
        float inva = 1.f / ola[r];
        float invb = 1.f / olb[r];
        opa[(size_t)r * IN_DIM]      = __float2bfloat16(o0a[r] * inva + (&r0a.x)[r]);
        opa[(size_t)r * IN_DIM + 16] = __float2bfloat16(o1a[r] * inva + (&r1a.x)[r]);
        opb[(size_t)r * IN_DIM]      = __float2bfloat16(o0b[r] * invb + (&r0b.x)[r]);
        opb[(size_t)r * IN_DIM + 16] = __float2bfloat16(o1b[r] * invb + (&r1b.x)[r]);
    }
}

// ---------------------------------------------------------------------------
// Kernel C: MFMA output projection.  out[b][n][d] = sum_c A[b][n][c]*Wo[d][c]
// ---------------------------------------------------------------------------
__global__ __launch_bounds__(256) void out_mfma(
    const bf16* __restrict__ A, const float* __restrict__ Wo,
    float* __restrict__ out)
{
    const int dh = blockIdx.y;
    const int b  = blockIdx.x >> 7;
    const int n0 = (blockIdx.x & 127) * 32;

    const int tid = threadIdx.x;
    const int wave = tid >> 6, lane = tid & 63;
    const int lg = lane >> 4, lc = lane & 15;
    const int wn = wave & 1, wdq = wave >> 1;

    __shared__ bf16 As[32 * 260];
    __shared__ bf16 Ws[2][128 * 36];

    {
        const bf16* Ab = A + ((size_t)b * NTOK + n0) * IN_DIM;
        for (int it = 0; it < 4; ++it) {
            int idx = it * 256 + tid;
            int r = idx >> 5, ch = idx & 31;
            bfrag v;
            v.v = *(const bf16x8*)(Ab + (size_t)r * IN_DIM + ch * 8);
            *(bf16x4*)&As[r * 260 + ch * 8]     = v.h[0];
            *(bf16x4*)&As[r * 260 + ch * 8 + 4] = v.h[1];
        }
    }
    const int wd = tid >> 1, wc = (tid & 1) * 16;
    const float* Wbase = Wo + (size_t)(dh * 128 + wd) * IN_DIM + wc;
    {
        float4 a = *(const float4*)(Wbase + 0);
        float4 bb = *(const float4*)(Wbase + 4);
        float4 cc = *(const float4*)(Wbase + 8);
        float4 dd = *(const float4*)(Wbase + 12);
        pack16(a, bb, cc, dd, &Ws[0][wd * 36 + wc]);
    }
    __syncthreads();

    f32x4 acc[4];
    #pragma unroll
    for (int t = 0; t < 4; ++t) acc[t] = f32x4{0.f, 0.f, 0.f, 0.f};

    for (int s = 0; s < 8; ++s) {
        const int c0 = s * 32;
        float4 pa, pb, pc, pd;
        if (s < 7) {
            const float* wn_ = Wbase + (s + 1) * 32;
            pa = *(const float4*)(wn_ + 0);
            pb = *(const float4*)(wn_ + 4);
            pc = *(const float4*)(wn_ + 8);
            pd = *(const float4*)(wn_ + 12);
        }
        bfrag af;
        const bf16* ap = &As[(wn * 16 + lc) * 260 + c0 + lg * 8];
        af.h[0] = *(const bf16x4*)ap;
        af.h[1] = *(const bf16x4*)(ap + 4);
        #pragma unroll
        for (int t = 0; t < 4; ++t) {
            bfrag wf;
            const bf16* wp = &Ws[s & 1][(wdq * 64 + t * 16 + lc) * 36 + lg * 8];
            wf.h[0] = *(const bf16x4*)wp;
            wf.h[1] = *(const bf16x4*)(wp + 4);
            acc[t] = __builtin_amdgcn_mfma_f32_16x16x32_bf16(af.v, wf.v, acc[t], 0, 0, 0);
        }
        if (s < 7) {
            __syncthreads();
            pack16(pa, pb, pc, pd, &Ws[(s + 1) & 1][wd * 36 + wc]);
            __syncthreads();
        }
    }

    const int nb = n0 + wn * 16 + lg * 4;
    #pragma unroll
    for (int t = 0; t < 4; ++t)
        #pragma unroll
        for (int r = 0; r < 4; ++r)
            out[((size_t)b * NTOK + nb + r) * IN_DIM + dh * 128 + wdq * 64 + t * 16 + lc]
                = acc[t][r];
}

// ---------------------------------------------------------------------------
extern "C" void kernel_launch(void* const* d_in, const int* in_sizes, int n_in,
                              void* d_out, int out_size, void* d_ws, size_t ws_size,
                              hipStream_t stream) {
    const float* tgt = (const float*)d_in[0];
    const float* src = (const float*)d_in[1];
    const float* Wq  = (const float*)d_in[2];
    const float* Wk  = (const float*)d_in[3];
    const float* Wv  = (const float*)d_in[4];
    const float* Wo  = (const float*)d_in[5];
    float* out = (float*)d_out;

    const size_t SZ = (size_t)BATCH * NTOK * IN_DIM * sizeof(bf16);  // 4 MiB
    char* w = (char*)d_ws;
    bf16* Qb  = (bf16*)(w);
    bf16* Kb  = (bf16*)(w + SZ);
    bf16* Vtb = (bf16*)(w + 2 * SZ);     // transposed V: [B][C][N]
    bf16* Wt  = (bf16*)(w + 3 * SZ);     // attn out + residual, [B][N][C]

    proj_mfma<<<dim3(256, 3, 2), 256, 0, stream>>>(tgt, src, Wq, Wk, Wv, Qb, Kb, Vtb);

    attn_mfma_kernel<<<512, 256, 0, stream>>>(Qb, Kb, Vtb, tgt, Wt);

    out_mfma<<<dim3(256, 2), 256, 0, stream>>>(Wt, Wo, out);
}

// Round 16
// 105.378 us; speedup vs baseline: 1.9604x; 1.9604x over previous
//
#include <hip/hip_runtime.h>
#include <hip/hip_bf16.h>

#define IN_DIM 256
#define NHEADS 8
#define HDIM 32
#define BATCH 2
#define NTOK 4096
#define QSCALE (0.17677669529663687f * 1.4426950408889634f)

typedef __hip_bfloat16 bf16;
typedef __attribute__((ext_vector_type(8))) short bf16x8;
typedef __attribute__((ext_vector_type(4))) short bf16x4;
typedef __attribute__((ext_vector_type(4))) float f32x4;

union bfrag { bf16x8 v; bf16x4 h[2]; };

__device__ __forceinline__ float b2f(bf16 x) { return __bfloat162float(x); }

#if __has_builtin(__builtin_amdgcn_exp2f)
__device__ __forceinline__ float fast_exp2(float x) { return __builtin_amdgcn_exp2f(x); }
#else
__device__ __forceinline__ float fast_exp2(float x) { return exp2f(x); }
#endif

__device__ __forceinline__ unsigned packbf2(float a, float b) {
    union { __hip_bfloat162 h; unsigned u; } c;
    c.h = __float22bfloat162_rn(float2{a, b});
    return c.u;
}

// 16x16 K=16 bf16 MFMA (identical per-lane k-placement in both operands).
#if __has_builtin(__builtin_amdgcn_mfma_f32_16x16x16bf16_1k)
__device__ __forceinline__ f32x4 mfma16(bf16x4 a, bf16x4 b, f32x4 c) {
    return __builtin_amdgcn_mfma_f32_16x16x16bf16_1k(a, b, c, 0, 0, 0);
}
#else
__device__ __forceinline__ f32x4 mfma16(bf16x4 a, bf16x4 b, f32x4 c) {
    bf16x8 az = {a[0], a[1], a[2], a[3], 0, 0, 0, 0};
    bf16x8 bz = {b[0], b[1], b[2], b[3], 0, 0, 0, 0};
    return __builtin_amdgcn_mfma_f32_16x16x32_bf16(az, bz, c, 0, 0, 0);
}
#endif

// pack 16 fp32 -> 16 bf16 into LDS (8B-aligned), as 4 uint2 writes
__device__ __forceinline__ void pack16(float4 a, float4 b, float4 c, float4 d,
                                       bf16* dst) {
    uint2 w0 = {packbf2(a.x, a.y), packbf2(a.z, a.w)};
    uint2 w1 = {packbf2(b.x, b.y), packbf2(b.z, b.w)};
    uint2 w2 = {packbf2(c.x, c.y), packbf2(c.z, c.w)};
    uint2 w3 = {packbf2(d.x, d.y), packbf2(d.z, d.w)};
    *(uint2*)(dst + 0)  = w0;
    *(uint2*)(dst + 4)  = w1;
    *(uint2*)(dst + 8)  = w2;
    *(uint2*)(dst + 12) = w3;
}

// ---------------------------------------------------------------------------
// Kernel A: MFMA QKV projection.  y[b][n][d] = sum_c X[b][c][n] * W[d][c]
// Q pre-scaled by QSCALE; V stored transposed Vt[b][d][n].
// grid (256, 3, 2); block 256 (4 waves).
// ---------------------------------------------------------------------------
__global__ __launch_bounds__(256) void proj_mfma(
    const float* __restrict__ tgt, const float* __restrict__ src,
    const float* __restrict__ Wq, const float* __restrict__ Wk,
    const float* __restrict__ Wv,
    bf16* __restrict__ Qo, bf16* __restrict__ Ko, bf16* __restrict__ Vo)
{
    const int which = blockIdx.y;
    const int dh = blockIdx.z;
    const int b  = blockIdx.x >> 7;
    const int n0 = (blockIdx.x & 127) * 32;
    const float* X = (which == 0) ? tgt : src;
    const float* W = (which == 0) ? Wq : (which == 1 ? Wk : Wv);

    const int tid = threadIdx.x;
    const int wave = tid >> 6, lane = tid & 63;
    const int lg = lane >> 4, lc = lane & 15;
    const int wn = wave & 1, wdq = wave >> 1;

    __shared__ bf16 As[32 * 260];              // [n][c], stride 260
    __shared__ bf16 Ws[2][128 * 36];           // [d][c-step], stride 36

    {
        const float* Xb = X + (size_t)b * IN_DIM * NTOK + n0;
        for (int it = 0; it < 8; ++it) {
            int idx = it * 256 + tid;
            int c = idx >> 3, j4 = idx & 7;
            float4 x = *(const float4*)(Xb + (size_t)c * NTOK + j4 * 4);
            As[(j4 * 4 + 0) * 260 + c] = __float2bfloat16(x.x);
            As[(j4 * 4 + 1) * 260 + c] = __float2bfloat16(x.y);
            As[(j4 * 4 + 2) * 260 + c] = __float2bfloat16(x.z);
            As[(j4 * 4 + 3) * 260 + c] = __float2bfloat16(x.w);
        }
    }
    const int wd = tid >> 1, wc = (tid & 1) * 16;
    const float* Wbase = W + (size_t)(dh * 128 + wd) * IN_DIM + wc;
    {
        float4 a = *(const float4*)(Wbase + 0);
        float4 bb = *(const float4*)(Wbase + 4);
        float4 cc = *(const float4*)(Wbase + 8);
        float4 dd = *(const float4*)(Wbase + 12);
        pack16(a, bb, cc, dd, &Ws[0][wd * 36 + wc]);
    }
    __syncthreads();

    f32x4 acc[4];
    #pragma unroll
    for (int t = 0; t < 4; ++t) acc[t] = f32x4{0.f, 0.f, 0.f, 0.f};

    for (int s = 0; s < 8; ++s) {
        const int c0 = s * 32;
        float4 pa, pb, pc, pd;
        if (s < 7) {
            const float* wn_ = Wbase + (s + 1) * 32;
            pa = *(const float4*)(wn_ + 0);
            pb = *(const float4*)(wn_ + 4);
            pc = *(const float4*)(wn_ + 8);
            pd = *(const float4*)(wn_ + 12);
        }
        bfrag af;
        const bf16* ap = &As[(wn * 16 + lc) * 260 + c0 + lg * 8];
        af.h[0] = *(const bf16x4*)ap;
        af.h[1] = *(const bf16x4*)(ap + 4);
        #pragma unroll
        for (int t = 0; t < 4; ++t) {
            bfrag wf;
            const bf16* wp = &Ws[s & 1][(wdq * 64 + t * 16 + lc) * 36 + lg * 8];
            wf.h[0] = *(const bf16x4*)wp;
            wf.h[1] = *(const bf16x4*)(wp + 4);
            acc[t] = __builtin_amdgcn_mfma_f32_16x16x32_bf16(af.v, wf.v, acc[t], 0, 0, 0);
        }
        if (s < 7) {
            __syncthreads();
            pack16(pa, pb, pc, pd, &Ws[(s + 1) & 1][wd * 36 + wc]);
            __syncthreads();
        }
    }

    const int nb = n0 + wn * 16 + lg * 4;
    if (which == 2) {
        #pragma unroll
        for (int t = 0; t < 4; ++t) {
            int d = dh * 128 + wdq * 64 + t * 16 + lc;
            uint2 pk;
            pk.x = packbf2(acc[t][0], acc[t][1]);
            pk.y = packbf2(acc[t][2], acc[t][3]);
            *(uint2*)(Vo + ((size_t)b * IN_DIM + d) * NTOK + nb) = pk;
        }
    } else {
        const float sc = (which == 0) ? QSCALE : 1.0f;
        bf16* O = (which == 0) ? Qo : Ko;
        #pragma unroll
        for (int t = 0; t < 4; ++t)
            #pragma unroll
            for (int r = 0; r < 4; ++r)
                O[((size_t)b * NTOK + nb + r) * IN_DIM + dh * 128 + wdq * 64 + t * 16 + lc]
                    = __float2bfloat16(acc[t][r] * sc);
    }
}

// ---------------------------------------------------------------------------
// Kernel B: MFMA flash attention, QBLK=32, RAW-BARRIER pipeline.
//   Key change vs r14: __syncthreads (which drains vmcnt(0) and serializes
//   the global prefetch into every iteration) is replaced by
//   {ds_write; issue next global loads; s_waitcnt lgkmcnt(0); raw s_barrier}.
//   The prefetch loads stay in flight ACROSS the barrier with a full compute
//   phase to complete (compiler auto-waits vmcnt before next ds_write).
//   Safety: double-buffered LDS + every ds_read consumed before next barrier.
// grid 512 (XCD-swizzled); block 256 (4 waves x 32 q).
// ---------------------------------------------------------------------------
__global__ __launch_bounds__(256) void attn_mfma_kernel(
    const bf16* __restrict__ Q, const bf16* __restrict__ K,
    const bf16* __restrict__ Vt, const float* __restrict__ tgt,
    bf16* __restrict__ Wt)
{
    const int blk = blockIdx.x;
    const int bh  = 2 * (blk & 7) + ((blk >> 3) & 1);
    const int qb  = blk >> 4;               // 0..31
    const int b = bh >> 3, h = bh & 7;
    const int tid  = threadIdx.x;
    const int wave = tid >> 6;
    const int lane = tid & 63;
    const int lg = lane >> 4, lc = lane & 15;
    const int qw = qb * 128 + wave * 32;

    __shared__ bf16 KL[2][64 * 40];          // [k][d] stride 40 (80B rows)
    __shared__ bf16 VL[2][32 * 72];          // [d][k] stride 72 (144B rows)

    const bf16x8 qfa = *(const bf16x8*)(Q + ((size_t)b * NTOK + qw + lc) * IN_DIM
                                          + h * HDIM + lg * 8);
    const bf16x8 qfb = *(const bf16x8*)(Q + ((size_t)b * NTOK + qw + 16 + lc) * IN_DIM
                                          + h * HDIM + lg * 8);

    bf16x4 ones4;
    #pragma unroll
    for (int i = 0; i < 4; ++i) ((short*)&ones4)[i] = (short)0x3F80;
    const f32x4 z = {0.f, 0.f, 0.f, 0.f};

    const int srow = tid >> 2, sd = (tid & 3) * 8;
    const int vrow = tid >> 3, vch = tid & 7;
    const int kwoff = srow * 40 + sd;
    const int vwoff = vrow * 72 + vch * 8;
    const int kroff = lc * 40 + lg * 8;                // +t*640
    const int vroff0 = lc * 72 + lg * 4;               // +t*16
    const int vroff1 = (16 + lc) * 72 + lg * 4;        // +t*16

    const bf16* Kp = K  + ((size_t)b * NTOK + srow) * IN_DIM + h * HDIM + sd;
    const bf16* Vp = Vt + ((size_t)b * IN_DIM + h * HDIM + vrow) * NTOK + vch * 8;

    f32x4 o0a = {0.f,0.f,0.f,0.f}, o1a = {0.f,0.f,0.f,0.f}, ola = {0.f,0.f,0.f,0.f};
    f32x4 o0b = {0.f,0.f,0.f,0.f}, o1b = {0.f,0.f,0.f,0.f}, olb = {0.f,0.f,0.f,0.f};

    bf16x8 kreg = *(const bf16x8*)Kp;
    bf16x8 vreg = *(const bf16x8*)Vp;
    Kp += (size_t)64 * IN_DIM;
    Vp += 64;

#define HALF(CUR)                                                              \
    {                                                                          \
        /* compiler auto-inserts vmcnt wait for kreg/vreg here */              \
        *(bf16x8*)&KL[CUR][kwoff] = kreg;                                      \
        *(bf16x8*)&VL[CUR][vwoff] = vreg;                                      \
        kreg = *(const bf16x8*)Kp;            /* stays in flight over barrier */ \
        vreg = *(const bf16x8*)Vp;                                             \
        Kp += (size_t)64 * IN_DIM;                                             \
        Vp += 64;                                                              \
        asm volatile("s_waitcnt lgkmcnt(0)" ::: "memory");  /* writes only */  \
        __builtin_amdgcn_s_barrier();         /* raw: no vmcnt drain */        \
        __builtin_amdgcn_sched_barrier(0);                                     \
        bf16x8 kf[4];                                                          \
        _Pragma("unroll")                                                      \
        for (int t = 0; t < 4; ++t)                                            \
            kf[t] = *(const bf16x8*)&KL[CUR][kroff + t * 640];                 \
        bf16x4 v0[4], v1[4];                                                   \
        _Pragma("unroll")                                                      \
        for (int t = 0; t < 4; ++t) {                                          \
            v0[t] = *(const bf16x4*)&VL[CUR][vroff0 + t * 16];                 \
            v1[t] = *(const bf16x4*)&VL[CUR][vroff1 + t * 16];                 \
        }                                                                      \
        f32x4 sa[4], sb[4];                                                    \
        __builtin_amdgcn_s_setprio(1);                                         \
        _Pragma("unroll")                                                      \
        for (int t = 0; t < 4; ++t) {                                          \
            sa[t] = __builtin_amdgcn_mfma_f32_16x16x32_bf16(kf[t], qfa, z, 0,0,0); \
            sb[t] = __builtin_amdgcn_mfma_f32_16x16x32_bf16(kf[t], qfb, z, 0,0,0); \
        }                                                                      \
        __builtin_amdgcn_s_setprio(0);                                         \
        _Pragma("unroll")                                                      \
        for (int t = 0; t < 4; ++t) {                                          \
            union { bf16x4 h; uint2 u; } pka, pkb;                             \
            pka.u.x = packbf2(fast_exp2(sa[t][0]), fast_exp2(sa[t][1]));       \
            pka.u.y = packbf2(fast_exp2(sa[t][2]), fast_exp2(sa[t][3]));       \
            pkb.u.x = packbf2(fast_exp2(sb[t][0]), fast_exp2(sb[t][1]));       \
            pkb.u.y = packbf2(fast_exp2(sb[t][2]), fast_exp2(sb[t][3]));       \
            __builtin_amdgcn_s_setprio(1);                                     \
            o0a = mfma16(pka.h, v0[t], o0a);                                   \
            o1a = mfma16(pka.h, v1[t], o1a);                                   \
            ola = mfma16(pka.h, ones4, ola);                                   \
            o0b = mfma16(pkb.h, v0[t], o0b);                                   \
            o1b = mfma16(pkb.h, v1[t], o1b);                                   \
            olb = mfma16(pkb.h, ones4, olb);                                   \
            __builtin_amdgcn_s_setprio(0);                                     \
        }                                                                      \
    }

    for (int it = 0; it < NTOK / 128; ++it) {
        HALF(0)
        HALF(1)
    }
#undef HALF

    // ---- epilogue: divide by l (D layout), add residual, store both q-tiles
    const float* tga = tgt + ((size_t)b * IN_DIM + h * HDIM + lc) * NTOK + qw + lg * 4;
    float4 r0a = *(const float4*)tga;
    float4 r1a = *(const float4*)(tga + (size_t)16 * NTOK);
    float4 r0b = *(const float4*)(tga + 16);
    float4 r1b = *(const float4*)(tga + (size_t)16 * NTOK + 16);

    bf16* opa = Wt + ((size_t)b * NTOK + qw + lg * 4) * IN_DIM + h * HDIM + lc;
    bf16* opb = opa + (size_t)16 * IN_DIM;
    #pragma unroll
    for (int r = 0; r < 4; ++r) {
        float inva = 1.f / ola[r];
        float invb = 1.f / olb[r];
        opa[(size_t)r * IN_DIM]      = __float2bfloat16(o0a[r] * inva + (&r0a.x)[r]);
        opa[(size_t)r * IN_DIM + 16] = __float2bfloat16(o1a[r] * inva + (&r1a.x)[r]);
        opb[(size_t)r * IN_DIM]      = __float2bfloat16(o0b[r] * invb + (&r0b.x)[r]);
        opb[(size_t)r * IN_DIM + 16] = __float2bfloat16(o1b[r] * invb + (&r1b.x)[r]);
    }
}

// ---------------------------------------------------------------------------
// Kernel C: MFMA output projection.  out[b][n][d] = sum_c A[b][n][c]*Wo[d][c]
// ---------------------------------------------------------------------------
__global__ __launch_bounds__(256) void out_mfma(
    const bf16* __restrict__ A, const float* __restrict__ Wo,
    float* __restrict__ out)
{
    const int dh = blockIdx.y;
    const int b  = blockIdx.x >> 7;
    const int n0 = (blockIdx.x & 127) * 32;

    const int tid = threadIdx.x;
    const int wave = tid >> 6, lane = tid & 63;
    const int lg = lane >> 4, lc = lane & 15;
    const int wn = wave & 1, wdq = wave >> 1;

    __shared__ bf16 As[32 * 260];
    __shared__ bf16 Ws[2][128 * 36];

    {
        const bf16* Ab = A + ((size_t)b * NTOK + n0) * IN_DIM;
        for (int it = 0; it < 4; ++it) {
            int idx = it * 256 + tid;
            int r = idx >> 5, ch = idx & 31;
            bfrag v;
            v.v = *(const bf16x8*)(Ab + (size_t)r * IN_DIM + ch * 8);
            *(bf16x4*)&As[r * 260 + ch * 8]     = v.h[0];
            *(bf16x4*)&As[r * 260 + ch * 8 + 4] = v.h[1];
        }
    }
    const int wd = tid >> 1, wc = (tid & 1) * 16;
    const float* Wbase = Wo + (size_t)(dh * 128 + wd) * IN_DIM + wc;
    {
        float4 a = *(const float4*)(Wbase + 0);
        float4 bb = *(const float4*)(Wbase + 4);
        float4 cc = *(const float4*)(Wbase + 8);
        float4 dd = *(const float4*)(Wbase + 12);
        pack16(a, bb, cc, dd, &Ws[0][wd * 36 + wc]);
    }
    __syncthreads();

    f32x4 acc[4];
    #pragma unroll
    for (int t = 0; t < 4; ++t) acc[t] = f32x4{0.f, 0.f, 0.f, 0.f};

    for (int s = 0; s < 8; ++s) {
        const int c0 = s * 32;
        float4 pa, pb, pc, pd;
        if (s < 7) {
            const float* wn_ = Wbase + (s + 1) * 32;
            pa = *(const float4*)(wn_ + 0);
            pb = *(const float4*)(wn_ + 4);
            pc = *(const float4*)(wn_ + 8);
            pd = *(const float4*)(wn_ + 12);
        }
        bfrag af;
        const bf16* ap = &As[(wn * 16 + lc) * 260 + c0 + lg * 8];
        af.h[0] = *(const bf16x4*)ap;
        af.h[1] = *(const bf16x4*)(ap + 4);
        #pragma unroll
        for (int t = 0; t < 4; ++t) {
            bfrag wf;
            const bf16* wp = &Ws[s & 1][(wdq * 64 + t * 16 + lc) * 36 + lg * 8];
            wf.h[0] = *(const bf16x4*)wp;
            wf.h[1] = *(const bf16x4*)(wp + 4);
            acc[t] = __builtin_amdgcn_mfma_f32_16x16x32_bf16(af.v, wf.v, acc[t], 0, 0, 0);
        }
        if (s < 7) {
            __syncthreads();
            pack16(pa, pb, pc, pd, &Ws[(s + 1) & 1][wd * 36 + wc]);
            __syncthreads();
        }
    }

    const int nb = n0 + wn * 16 + lg * 4;
    #pragma unroll
    for (int t = 0; t < 4; ++t)
        #pragma unroll
        for (int r = 0; r < 4; ++r)
            out[((size_t)b * NTOK + nb + r) * IN_DIM + dh * 128 + wdq * 64 + t * 16 + lc]
                = acc[t][r];
}

// ---------------------------------------------------------------------------
extern "C" void kernel_launch(void* const* d_in, const int* in_sizes, int n_in,
                              void* d_out, int out_size, void* d_ws, size_t ws_size,
                              hipStream_t stream) {
    const float* tgt = (const float*)d_in[0];
    const float* src = (const float*)d_in[1];
    const float* Wq  = (const float*)d_in[2];
    const float* Wk  = (const float*)d_in[3];
    const float* Wv  = (const float*)d_in[4];
    const float* Wo  = (const float*)d_in[5];
    float* out = (float*)d_out;

    const size_t SZ = (size_t)BATCH * NTOK * IN_DIM * sizeof(bf16);  // 4 MiB
    char* w = (char*)d_ws;
    bf16* Qb  = (bf16*)(w);
    bf16* Kb  = (bf16*)(w + SZ);
    bf16* Vtb = (bf16*)(w + 2 * SZ);     // transposed V: [B][C][N]
    bf16* Wt  = (bf16*)(w + 3 * SZ);     // attn out + residual, [B][N][C]

    proj_mfma<<<dim3(256, 3, 2), 256, 0, stream>>>(tgt, src, Wq, Wk, Wv, Qb, Kb, Vtb);

    attn_mfma_kernel<<<512, 256, 0, stream>>>(Qb, Kb, Vtb, tgt, Wt);

    out_mfma<<<dim3(256, 2), 256, 0, stream>>>(Wt, Wo, out);
}

// Round 17
// 97.789 us; speedup vs baseline: 2.1125x; 1.0776x over previous
//
#include <hip/hip_runtime.h>
#include <hip/hip_bf16.h>

#define IN_DIM 256
#define NHEADS 8
#define HDIM 32
#define BATCH 2
#define NTOK 4096
#define QSCALE (0.17677669529663687f * 1.4426950408889634f)

typedef __hip_bfloat16 bf16;
typedef __attribute__((ext_vector_type(8))) short bf16x8;
typedef __attribute__((ext_vector_type(4))) short bf16x4;
typedef __attribute__((ext_vector_type(4))) float f32x4;

union bfrag { bf16x8 v; bf16x4 h[2]; };

__device__ __forceinline__ float b2f(bf16 x) { return __bfloat162float(x); }

#if __has_builtin(__builtin_amdgcn_exp2f)
__device__ __forceinline__ float fast_exp2(float x) { return __builtin_amdgcn_exp2f(x); }
#else
__device__ __forceinline__ float fast_exp2(float x) { return exp2f(x); }
#endif

__device__ __forceinline__ unsigned packbf2(float a, float b) {
    union { __hip_bfloat162 h; unsigned u; } c;
    c.h = __float22bfloat162_rn(float2{a, b});
    return c.u;
}

// pack 16 fp32 -> 16 bf16 into LDS (8B-aligned), as 4 uint2 writes
__device__ __forceinline__ void pack16(float4 a, float4 b, float4 c, float4 d,
                                       bf16* dst) {
    uint2 w0 = {packbf2(a.x, a.y), packbf2(a.z, a.w)};
    uint2 w1 = {packbf2(b.x, b.y), packbf2(b.z, b.w)};
    uint2 w2 = {packbf2(c.x, c.y), packbf2(c.z, c.w)};
    uint2 w3 = {packbf2(d.x, d.y), packbf2(d.z, d.w)};
    *(uint2*)(dst + 0)  = w0;
    *(uint2*)(dst + 4)  = w1;
    *(uint2*)(dst + 8)  = w2;
    *(uint2*)(dst + 12) = w3;
}

// ---------------------------------------------------------------------------
// Kernel A: MFMA QKV projection.  y[b][n][d] = sum_c X[b][c][n] * W[d][c]
// Q pre-scaled by QSCALE; V stored transposed Vt[b][d][n].
// grid (256, 3, 2); block 256 (4 waves).
// ---------------------------------------------------------------------------
__global__ __launch_bounds__(256) void proj_mfma(
    const float* __restrict__ tgt, const float* __restrict__ src,
    const float* __restrict__ Wq, const float* __restrict__ Wk,
    const float* __restrict__ Wv,
    bf16* __restrict__ Qo, bf16* __restrict__ Ko, bf16* __restrict__ Vo)
{
    const int which = blockIdx.y;
    const int dh = blockIdx.z;
    const int b  = blockIdx.x >> 7;
    const int n0 = (blockIdx.x & 127) * 32;
    const float* X = (which == 0) ? tgt : src;
    const float* W = (which == 0) ? Wq : (which == 1 ? Wk : Wv);

    const int tid = threadIdx.x;
    const int wave = tid >> 6, lane = tid & 63;
    const int lg = lane >> 4, lc = lane & 15;
    const int wn = wave & 1, wdq = wave >> 1;

    __shared__ bf16 As[32 * 260];              // [n][c], stride 260
    __shared__ bf16 Ws[2][128 * 36];           // [d][c-step], stride 36

    {
        const float* Xb = X + (size_t)b * IN_DIM * NTOK + n0;
        for (int it = 0; it < 8; ++it) {
            int idx = it * 256 + tid;
            int c = idx >> 3, j4 = idx & 7;
            float4 x = *(const float4*)(Xb + (size_t)c * NTOK + j4 * 4);
            As[(j4 * 4 + 0) * 260 + c] = __float2bfloat16(x.x);
            As[(j4 * 4 + 1) * 260 + c] = __float2bfloat16(x.y);
            As[(j4 * 4 + 2) * 260 + c] = __float2bfloat16(x.z);
            As[(j4 * 4 + 3) * 260 + c] = __float2bfloat16(x.w);
        }
    }
    const int wd = tid >> 1, wc = (tid & 1) * 16;
    const float* Wbase = W + (size_t)(dh * 128 + wd) * IN_DIM + wc;
    {
        float4 a = *(const float4*)(Wbase + 0);
        float4 bb = *(const float4*)(Wbase + 4);
        float4 cc = *(const float4*)(Wbase + 8);
        float4 dd = *(const float4*)(Wbase + 12);
        pack16(a, bb, cc, dd, &Ws[0][wd * 36 + wc]);
    }
    __syncthreads();

    f32x4 acc[4];
    #pragma unroll
    for (int t = 0; t < 4; ++t) acc[t] = f32x4{0.f, 0.f, 0.f, 0.f};

    for (int s = 0; s < 8; ++s) {
        const int c0 = s * 32;
        float4 pa, pb, pc, pd;
        if (s < 7) {
            const float* wn_ = Wbase + (s + 1) * 32;
            pa = *(const float4*)(wn_ + 0);
            pb = *(const float4*)(wn_ + 4);
            pc = *(const float4*)(wn_ + 8);
            pd = *(const float4*)(wn_ + 12);
        }
        bfrag af;
        const bf16* ap = &As[(wn * 16 + lc) * 260 + c0 + lg * 8];
        af.h[0] = *(const bf16x4*)ap;
        af.h[1] = *(const bf16x4*)(ap + 4);
        #pragma unroll
        for (int t = 0; t < 4; ++t) {
            bfrag wf;
            const bf16* wp = &Ws[s & 1][(wdq * 64 + t * 16 + lc) * 36 + lg * 8];
            wf.h[0] = *(const bf16x4*)wp;
            wf.h[1] = *(const bf16x4*)(wp + 4);
            acc[t] = __builtin_amdgcn_mfma_f32_16x16x32_bf16(af.v, wf.v, acc[t], 0, 0, 0);
        }
        if (s < 7) {
            __syncthreads();
            pack16(pa, pb, pc, pd, &Ws[(s + 1) & 1][wd * 36 + wc]);
            __syncthreads();
        }
    }

    const int nb = n0 + wn * 16 + lg * 4;
    if (which == 2) {
        #pragma unroll
        for (int t = 0; t < 4; ++t) {
            int d = dh * 128 + wdq * 64 + t * 16 + lc;
            uint2 pk;
            pk.x = packbf2(acc[t][0], acc[t][1]);
            pk.y = packbf2(acc[t][2], acc[t][3]);
            *(uint2*)(Vo + ((size_t)b * IN_DIM + d) * NTOK + nb) = pk;
        }
    } else {
        const float sc = (which == 0) ? QSCALE : 1.0f;
        bf16* O = (which == 0) ? Qo : Ko;
        #pragma unroll
        for (int t = 0; t < 4; ++t)
            #pragma unroll
            for (int r = 0; r < 4; ++r)
                O[((size_t)b * NTOK + nb + r) * IN_DIM + dh * 128 + wdq * 64 + t * 16 + lc]
                    = __float2bfloat16(acc[t][r] * sc);
    }
}

// ---------------------------------------------------------------------------
// Kernel B: MFMA flash attention, QBLK=32, K=32 slot-merged PV.
//   - swapped QK^T: lane holds S[kv=t*16+lg*4+r][q=lc]
//   - PV + l as NATIVE 16x16x32 MFMAs via slot-merge: A = [P(t),P(t+1)],
//     B = [V(t),V(t+1)] (two LDS b64s), ones8 column folds l into the same
//     contraction.  12 MFMAs/iter (was 24 K=16 + possible fallback mov-storm).
//   - KL stride 40, VL stride 72 (all LDS accesses <=2-way = free)
//   - no-max softmax via raw v_exp_f32; x2-unrolled dbuf; __syncthreads/iter
// grid 512 (XCD-swizzled); block 256 (4 waves x 32 q).
// ---------------------------------------------------------------------------
__global__ __launch_bounds__(256) void attn_mfma_kernel(
    const bf16* __restrict__ Q, const bf16* __restrict__ K,
    const bf16* __restrict__ Vt, const float* __restrict__ tgt,
    bf16* __restrict__ Wt)
{
    const int blk = blockIdx.x;
    const int bh  = 2 * (blk & 7) + ((blk >> 3) & 1);
    const int qb  = blk >> 4;               // 0..31
    const int b = bh >> 3, h = bh & 7;
    const int tid  = threadIdx.x;
    const int wave = tid >> 6;
    const int lane = tid & 63;
    const int lg = lane >> 4, lc = lane & 15;
    const int qw = qb * 128 + wave * 32;

    __shared__ bf16 KL[2][64 * 40];          // [k][d] stride 40 (80B rows)
    __shared__ bf16 VL[2][32 * 72];          // [d][k] stride 72 (144B rows)

    const bf16x8 qfa = *(const bf16x8*)(Q + ((size_t)b * NTOK + qw + lc) * IN_DIM
                                          + h * HDIM + lg * 8);
    const bf16x8 qfb = *(const bf16x8*)(Q + ((size_t)b * NTOK + qw + 16 + lc) * IN_DIM
                                          + h * HDIM + lg * 8);

    bf16x8 ones8;
    #pragma unroll
    for (int i = 0; i < 8; ++i) ((short*)&ones8)[i] = (short)0x3F80;
    const f32x4 z = {0.f, 0.f, 0.f, 0.f};

    const int srow = tid >> 2, sd = (tid & 3) * 8;
    const int vrow = tid >> 3, vch = tid & 7;
    const int kwoff = srow * 40 + sd;
    const int vwoff = vrow * 72 + vch * 8;
    const int kroff = lc * 40 + lg * 8;                // +t*640
    const int vroff0 = lc * 72 + lg * 4;               // +t*16
    const int vroff1 = (16 + lc) * 72 + lg * 4;        // +t*16

    const bf16* Kp = K  + ((size_t)b * NTOK + srow) * IN_DIM + h * HDIM + sd;
    const bf16* Vp = Vt + ((size_t)b * IN_DIM + h * HDIM + vrow) * NTOK + vch * 8;

    f32x4 o0a = {0.f,0.f,0.f,0.f}, o1a = {0.f,0.f,0.f,0.f}, ola = {0.f,0.f,0.f,0.f};
    f32x4 o0b = {0.f,0.f,0.f,0.f}, o1b = {0.f,0.f,0.f,0.f}, olb = {0.f,0.f,0.f,0.f};

    bf16x8 kreg = *(const bf16x8*)Kp;
    bf16x8 vreg = *(const bf16x8*)Vp;
    Kp += (size_t)64 * IN_DIM;
    Vp += 64;

#define HALF(CUR)                                                              \
    {                                                                          \
        *(bf16x8*)&KL[CUR][kwoff] = kreg;                                      \
        *(bf16x8*)&VL[CUR][vwoff] = vreg;                                      \
        kreg = *(const bf16x8*)Kp;                                             \
        vreg = *(const bf16x8*)Vp;                                             \
        Kp += (size_t)64 * IN_DIM;                                             \
        Vp += 64;                                                              \
        __syncthreads();                                                       \
        bf16x8 kf[4];                                                          \
        _Pragma("unroll")                                                      \
        for (int t = 0; t < 4; ++t)                                            \
            kf[t] = *(const bf16x8*)&KL[CUR][kroff + t * 640];                 \
        bf16x4 v0[4], v1[4];                                                   \
        _Pragma("unroll")                                                      \
        for (int t = 0; t < 4; ++t) {                                          \
            v0[t] = *(const bf16x4*)&VL[CUR][vroff0 + t * 16];                 \
            v1[t] = *(const bf16x4*)&VL[CUR][vroff1 + t * 16];                 \
        }                                                                      \
        f32x4 sa[4], sb[4];                                                    \
        __builtin_amdgcn_s_setprio(1);                                         \
        _Pragma("unroll")                                                      \
        for (int t = 0; t < 4; ++t) {                                          \
            sa[t] = __builtin_amdgcn_mfma_f32_16x16x32_bf16(kf[t], qfa, z, 0,0,0); \
            sb[t] = __builtin_amdgcn_mfma_f32_16x16x32_bf16(kf[t], qfb, z, 0,0,0); \
        }                                                                      \
        __builtin_amdgcn_s_setprio(0);                                         \
        _Pragma("unroll")                                                      \
        for (int tcp = 0; tcp < 2; ++tcp) {                                    \
            union { bf16x8 v; uint4 u; } pa, pb;                               \
            pa.u.x = packbf2(fast_exp2(sa[2*tcp][0]),   fast_exp2(sa[2*tcp][1]));   \
            pa.u.y = packbf2(fast_exp2(sa[2*tcp][2]),   fast_exp2(sa[2*tcp][3]));   \
            pa.u.z = packbf2(fast_exp2(sa[2*tcp+1][0]), fast_exp2(sa[2*tcp+1][1])); \
            pa.u.w = packbf2(fast_exp2(sa[2*tcp+1][2]), fast_exp2(sa[2*tcp+1][3])); \
            pb.u.x = packbf2(fast_exp2(sb[2*tcp][0]),   fast_exp2(sb[2*tcp][1]));   \
            pb.u.y = packbf2(fast_exp2(sb[2*tcp][2]),   fast_exp2(sb[2*tcp][3]));   \
            pb.u.z = packbf2(fast_exp2(sb[2*tcp+1][0]), fast_exp2(sb[2*tcp+1][1])); \
            pb.u.w = packbf2(fast_exp2(sb[2*tcp+1][2]), fast_exp2(sb[2*tcp+1][3])); \
            bfrag B0, B1;                                                      \
            B0.h[0] = v0[2*tcp]; B0.h[1] = v0[2*tcp+1];                        \
            B1.h[0] = v1[2*tcp]; B1.h[1] = v1[2*tcp+1];                        \
            __builtin_amdgcn_s_setprio(1);                                     \
            o0a = __builtin_amdgcn_mfma_f32_16x16x32_bf16(pa.v, B0.v, o0a, 0,0,0); \
            o1a = __builtin_amdgcn_mfma_f32_16x16x32_bf16(pa.v, B1.v, o1a, 0,0,0); \
            ola = __builtin_amdgcn_mfma_f32_16x16x32_bf16(pa.v, ones8, ola, 0,0,0); \
            o0b = __builtin_amdgcn_mfma_f32_16x16x32_bf16(pb.v, B0.v, o0b, 0,0,0); \
            o1b = __builtin_amdgcn_mfma_f32_16x16x32_bf16(pb.v, B1.v, o1b, 0,0,0); \
            olb = __builtin_amdgcn_mfma_f32_16x16x32_bf16(pb.v, ones8, olb, 0,0,0); \
            __builtin_amdgcn_s_setprio(0);                                     \
        }                                                                      \
    }

    for (int it = 0; it < NTOK / 128; ++it) {
        HALF(0)
        HALF(1)
    }
#undef HALF

    // ---- epilogue: divide by l (D layout), add residual, store both q-tiles
    const float* tga = tgt + ((size_t)b * IN_DIM + h * HDIM + lc) * NTOK + qw + lg * 4;
    float4 r0a = *(const float4*)tga;
    float4 r1a = *(const float4*)(tga + (size_t)16 * NTOK);
    float4 r0b = *(const float4*)(tga + 16);
    float4 r1b = *(const float4*)(tga + (size_t)16 * NTOK + 16);

    bf16* opa = Wt + ((size_t)b * NTOK + qw + lg * 4) * IN_DIM + h * HDIM + lc;
    bf16* opb = opa + (size_t)16 * IN_DIM;
    #pragma unroll
    for (int r = 0; r < 4; ++r) {
        float inva = 1.f / ola[r];
        float invb = 1.f / olb[r];
        opa[(size_t)r * IN_DIM]      = __float2bfloat16(o0a[r] * inva + (&r0a.x)[r]);
        opa[(size_t)r * IN_DIM + 16] = __float2bfloat16(o1a[r] * inva + (&r1a.x)[r]);
        opb[(size_t)r * IN_DIM]      = __float2bfloat16(o0b[r] * invb + (&r0b.x)[r]);
        opb[(size_t)r * IN_DIM + 16] = __float2bfloat16(o1b[r] * invb + (&r1b.x)[r]);
    }
}

// ---------------------------------------------------------------------------
// Kernel C: MFMA output projection.  out[b][n][d] = sum_c A[b][n][c]*Wo[d][c]
// ---------------------------------------------------------------------------
__global__ __launch_bounds__(256) void out_mfma(
    const bf16* __restrict__ A, const float* __restrict__ Wo,
    float* __restrict__ out)
{
    const int dh = blockIdx.y;
    const int b  = blockIdx.x >> 7;
    const int n0 = (blockIdx.x & 127) * 32;

    const int tid = threadIdx.x;
    const int wave = tid >> 6, lane = tid & 63;
    const int lg = lane >> 4, lc = lane & 15;
    const int wn = wave & 1, wdq = wave >> 1;

    __shared__ bf16 As[32 * 260];
    __shared__ bf16 Ws[2][128 * 36];

    {
        const bf16* Ab = A + ((size_t)b * NTOK + n0) * IN_DIM;
        for (int it = 0; it < 4; ++it) {
            int idx = it * 256 + tid;
            int r = idx >> 5, ch = idx & 31;
            bfrag v;
            v.v = *(const bf16x8*)(Ab + (size_t)r * IN_DIM + ch * 8);
            *(bf16x4*)&As[r * 260 + ch * 8]     = v.h[0];
            *(bf16x4*)&As[r * 260 + ch * 8 + 4] = v.h[1];
        }
    }
    const int wd = tid >> 1, wc = (tid & 1) * 16;
    const float* Wbase = Wo + (size_t)(dh * 128 + wd) * IN_DIM + wc;
    {
        float4 a = *(const float4*)(Wbase + 0);
        float4 bb = *(const float4*)(Wbase + 4);
        float4 cc = *(const float4*)(Wbase + 8);
        float4 dd = *(const float4*)(Wbase + 12);
        pack16(a, bb, cc, dd, &Ws[0][wd * 36 + wc]);
    }
    __syncthreads();

    f32x4 acc[4];
    #pragma unroll
    for (int t = 0; t < 4; ++t) acc[t] = f32x4{0.f, 0.f, 0.f, 0.f};

    for (int s = 0; s < 8; ++s) {
        const int c0 = s * 32;
        float4 pa, pb, pc, pd;
        if (s < 7) {
            const float* wn_ = Wbase + (s + 1) * 32;
            pa = *(const float4*)(wn_ + 0);
            pb = *(const float4*)(wn_ + 4);
            pc = *(const float4*)(wn_ + 8);
            pd = *(const float4*)(wn_ + 12);
        }
        bfrag af;
        const bf16* ap = &As[(wn * 16 + lc) * 260 + c0 + lg * 8];
        af.h[0] = *(const bf16x4*)ap;
        af.h[1] = *(const bf16x4*)(ap + 4);
        #pragma unroll
        for (int t = 0; t < 4; ++t) {
            bfrag wf;
            const bf16* wp = &Ws[s & 1][(wdq * 64 + t * 16 + lc) * 36 + lg * 8];
            wf.h[0] = *(const bf16x4*)wp;
            wf.h[1] = *(const bf16x4*)(wp + 4);
            acc[t] = __builtin_amdgcn_mfma_f32_16x16x32_bf16(af.v, wf.v, acc[t], 0, 0, 0);
        }
        if (s < 7) {
            __syncthreads();
            pack16(pa, pb, pc, pd, &Ws[(s + 1) & 1][wd * 36 + wc]);
            __syncthreads();
        }
    }

    const int nb = n0 + wn * 16 + lg * 4;
    #pragma unroll
    for (int t = 0; t < 4; ++t)
        #pragma unroll
        for (int r = 0; r < 4; ++r)
            out[((size_t)b * NTOK + nb + r) * IN_DIM + dh * 128 + wdq * 64 + t * 16 + lc]
                = acc[t][r];
}

// ---------------------------------------------------------------------------
extern "C" void kernel_launch(void* const* d_in, const int* in_sizes, int n_in,
                              void* d_out, int out_size, void* d_ws, size_t ws_size,
                              hipStream_t stream) {
    const float* tgt = (const float*)d_in[0];
    const float* src = (const float*)d_in[1];
    const float* Wq  = (const float*)d_in[2];
    const float* Wk  = (const float*)d_in[3];
    const float* Wv  = (const float*)d_in[4];
    const float* Wo  = (const float*)d_in[5];
    float* out = (float*)d_out;

    const size_t SZ = (size_t)BATCH * NTOK * IN_DIM * sizeof(bf16);  // 4 MiB
    char* w = (char*)d_ws;
    bf16* Qb  = (bf16*)(w);
    bf16* Kb  = (bf16*)(w + SZ);
    bf16* Vtb = (bf16*)(w + 2 * SZ);     // transposed V: [B][C][N]
    bf16* Wt  = (bf16*)(w + 3 * SZ);     // attn out + residual, [B][N][C]

    proj_mfma<<<dim3(256, 3, 2), 256, 0, stream>>>(tgt, src, Wq, Wk, Wv, Qb, Kb, Vtb);

    attn_mfma_kernel<<<512, 256, 0, stream>>>(Qb, Kb, Vtb, tgt, Wt);

    out_mfma<<<dim3(256, 2), 256, 0, stream>>>(Wt, Wo, out);
}

// Round 18
// 83.542 us; speedup vs baseline: 2.4728x; 1.1705x over previous
//
#include <hip/hip_runtime.h>
#include <hip/hip_bf16.h>

#define IN_DIM 256
#define NHEADS 8
#define HDIM 32
#define BATCH 2
#define NTOK 4096
#define QSCALE (0.17677669529663687f * 1.4426950408889634f)

typedef __hip_bfloat16 bf16;
typedef __attribute__((ext_vector_type(8))) short bf16x8;
typedef __attribute__((ext_vector_type(4))) short bf16x4;
typedef __attribute__((ext_vector_type(4))) float f32x4;

union bfrag { bf16x8 v; bf16x4 h[2]; };

__device__ __forceinline__ float b2f(bf16 x) { return __bfloat162float(x); }

#if __has_builtin(__builtin_amdgcn_exp2f)
__device__ __forceinline__ float fast_exp2(float x) { return __builtin_amdgcn_exp2f(x); }
#else
__device__ __forceinline__ float fast_exp2(float x) { return exp2f(x); }
#endif

__device__ __forceinline__ unsigned packbf2(float a, float b) {
    union { __hip_bfloat162 h; unsigned u; } c;
    c.h = __float22bfloat162_rn(float2{a, b});
    return c.u;
}

// pack 16 fp32 -> 16 bf16 into LDS (8B-aligned), as 4 uint2 writes
__device__ __forceinline__ void pack16(float4 a, float4 b, float4 c, float4 d,
                                       bf16* dst) {
    uint2 w0 = {packbf2(a.x, a.y), packbf2(a.z, a.w)};
    uint2 w1 = {packbf2(b.x, b.y), packbf2(b.z, b.w)};
    uint2 w2 = {packbf2(c.x, c.y), packbf2(c.z, c.w)};
    uint2 w3 = {packbf2(d.x, d.y), packbf2(d.z, d.w)};
    *(uint2*)(dst + 0)  = w0;
    *(uint2*)(dst + 4)  = w1;
    *(uint2*)(dst + 8)  = w2;
    *(uint2*)(dst + 12) = w3;
}

// ---------------------------------------------------------------------------
// Kernel A: MFMA QKV projection.  y[b][n][d] = sum_c X[b][c][n] * W[d][c]
// Q pre-scaled by QSCALE; V stored transposed Vt[b][d][n].
// grid (256, 3, 2); block 256 (4 waves).
// ---------------------------------------------------------------------------
__global__ __launch_bounds__(256) void proj_mfma(
    const float* __restrict__ tgt, const float* __restrict__ src,
    const float* __restrict__ Wq, const float* __restrict__ Wk,
    const float* __restrict__ Wv,
    bf16* __restrict__ Qo, bf16* __restrict__ Ko, bf16* __restrict__ Vo)
{
    const int which = blockIdx.y;
    const int dh = blockIdx.z;
    const int b  = blockIdx.x >> 7;
    const int n0 = (blockIdx.x & 127) * 32;
    const float* X = (which == 0) ? tgt : src;
    const float* W = (which == 0) ? Wq : (which == 1 ? Wk : Wv);

    const int tid = threadIdx.x;
    const int wave = tid >> 6, lane = tid & 63;
    const int lg = lane >> 4, lc = lane & 15;
    const int wn = wave & 1, wdq = wave >> 1;

    __shared__ bf16 As[32 * 260];              // [n][c], stride 260
    __shared__ bf16 Ws[2][128 * 36];           // [d][c-step], stride 36

    {
        const float* Xb = X + (size_t)b * IN_DIM * NTOK + n0;
        for (int it = 0; it < 8; ++it) {
            int idx = it * 256 + tid;
            int c = idx >> 3, j4 = idx & 7;
            float4 x = *(const float4*)(Xb + (size_t)c * NTOK + j4 * 4);
            As[(j4 * 4 + 0) * 260 + c] = __float2bfloat16(x.x);
            As[(j4 * 4 + 1) * 260 + c] = __float2bfloat16(x.y);
            As[(j4 * 4 + 2) * 260 + c] = __float2bfloat16(x.z);
            As[(j4 * 4 + 3) * 260 + c] = __float2bfloat16(x.w);
        }
    }
    const int wd = tid >> 1, wc = (tid & 1) * 16;
    const float* Wbase = W + (size_t)(dh * 128 + wd) * IN_DIM + wc;
    {
        float4 a = *(const float4*)(Wbase + 0);
        float4 bb = *(const float4*)(Wbase + 4);
        float4 cc = *(const float4*)(Wbase + 8);
        float4 dd = *(const float4*)(Wbase + 12);
        pack16(a, bb, cc, dd, &Ws[0][wd * 36 + wc]);
    }
    __syncthreads();

    f32x4 acc[4];
    #pragma unroll
    for (int t = 0; t < 4; ++t) acc[t] = f32x4{0.f, 0.f, 0.f, 0.f};

    for (int s = 0; s < 8; ++s) {
        const int c0 = s * 32;
        float4 pa, pb, pc, pd;
        if (s < 7) {
            const float* wn_ = Wbase + (s + 1) * 32;
            pa = *(const float4*)(wn_ + 0);
            pb = *(const float4*)(wn_ + 4);
            pc = *(const float4*)(wn_ + 8);
            pd = *(const float4*)(wn_ + 12);
        }
        bfrag af;
        const bf16* ap = &As[(wn * 16 + lc) * 260 + c0 + lg * 8];
        af.h[0] = *(const bf16x4*)ap;
        af.h[1] = *(const bf16x4*)(ap + 4);
        #pragma unroll
        for (int t = 0; t < 4; ++t) {
            bfrag wf;
            const bf16* wp = &Ws[s & 1][(wdq * 64 + t * 16 + lc) * 36 + lg * 8];
            wf.h[0] = *(const bf16x4*)wp;
            wf.h[1] = *(const bf16x4*)(wp + 4);
            acc[t] = __builtin_amdgcn_mfma_f32_16x16x32_bf16(af.v, wf.v, acc[t], 0, 0, 0);
        }
        if (s < 7) {
            __syncthreads();
            pack16(pa, pb, pc, pd, &Ws[(s + 1) & 1][wd * 36 + wc]);
            __syncthreads();
        }
    }

    const int nb = n0 + wn * 16 + lg * 4;
    if (which == 2) {
        #pragma unroll
        for (int t = 0; t < 4; ++t) {
            int d = dh * 128 + wdq * 64 + t * 16 + lc;
            uint2 pk;
            pk.x = packbf2(acc[t][0], acc[t][1]);
            pk.y = packbf2(acc[t][2], acc[t][3]);
            *(uint2*)(Vo + ((size_t)b * IN_DIM + d) * NTOK + nb) = pk;
        }
    } else {
        const float sc = (which == 0) ? QSCALE : 1.0f;
        bf16* O = (which == 0) ? Qo : Ko;
        #pragma unroll
        for (int t = 0; t < 4; ++t)
            #pragma unroll
            for (int r = 0; r < 4; ++r)
                O[((size_t)b * NTOK + nb + r) * IN_DIM + dh * 128 + wdq * 64 + t * 16 + lc]
                    = __float2bfloat16(acc[t][r] * sc);
    }
}

// ---------------------------------------------------------------------------
// Kernel B: MFMA flash attention, 8 waves, intra-block kv-split.
//   - group g = wave>>2 handles kv in [g*2048, g*2048+2048), same 128 q rows
//   - no-max softmax => O and l are pure sums: partials combine by ADDITION
//     (group 1 -> LDS, group 0 adds + epilogue)
//   - per-group double-buffered KL/VL; K=32 slot-merged PV + ones-column l
//   - occupancy: 16 waves/CU (was 8) to saturate the trans (exp) pipe
// grid 512 (XCD-swizzled); block 512.
// ---------------------------------------------------------------------------
__global__ __launch_bounds__(512) void attn_mfma_kernel(
    const bf16* __restrict__ Q, const bf16* __restrict__ K,
    const bf16* __restrict__ Vt, const float* __restrict__ tgt,
    bf16* __restrict__ Wt)
{
    const int blk = blockIdx.x;
    const int bh  = 2 * (blk & 7) + ((blk >> 3) & 1);
    const int qb  = blk >> 4;               // 0..31
    const int b = bh >> 3, h = bh & 7;
    const int tid  = threadIdx.x;
    const int wave = tid >> 6;
    const int grp  = wave >> 2;             // kv-half
    const int wl   = wave & 3;              // wave within group
    const int lane = tid & 63;
    const int lg = lane >> 4, lc = lane & 15;
    const int qw = qb * 128 + wl * 32;

    __shared__ bf16 KL[2][2][64 * 40];      // [grp][dbuf][k][d] stride 40
    __shared__ bf16 VL[2][2][32 * 72];      // [grp][dbuf][d][k] stride 72
    __shared__ float redC[4][64 * 24];      // combine buffer (24 f32/lane)

    const bf16x8 qfa = *(const bf16x8*)(Q + ((size_t)b * NTOK + qw + lc) * IN_DIM
                                          + h * HDIM + lg * 8);
    const bf16x8 qfb = *(const bf16x8*)(Q + ((size_t)b * NTOK + qw + 16 + lc) * IN_DIM
                                          + h * HDIM + lg * 8);

    bf16x8 ones8;
    #pragma unroll
    for (int i = 0; i < 8; ++i) ((short*)&ones8)[i] = (short)0x3F80;
    const f32x4 z = {0.f, 0.f, 0.f, 0.f};

    const int tg   = tid & 255;             // thread index within group
    const int srow = tg >> 2, sd = (tg & 3) * 8;
    const int vrow = tg >> 3, vch = tg & 7;
    const int kwoff = srow * 40 + sd;
    const int vwoff = vrow * 72 + vch * 8;
    const int kroff = lc * 40 + lg * 8;                // +t*640
    const int vroff0 = lc * 72 + lg * 4;               // +t*16
    const int vroff1 = (16 + lc) * 72 + lg * 4;        // +t*16

    const bf16* Kp = K  + ((size_t)b * NTOK + grp * 2048 + srow) * IN_DIM + h * HDIM + sd;
    const bf16* Vp = Vt + ((size_t)b * IN_DIM + h * HDIM + vrow) * NTOK + grp * 2048 + vch * 8;

    f32x4 o0a = {0.f,0.f,0.f,0.f}, o1a = {0.f,0.f,0.f,0.f}, ola = {0.f,0.f,0.f,0.f};
    f32x4 o0b = {0.f,0.f,0.f,0.f}, o1b = {0.f,0.f,0.f,0.f}, olb = {0.f,0.f,0.f,0.f};

    bf16x8 kreg = *(const bf16x8*)Kp;
    bf16x8 vreg = *(const bf16x8*)Vp;
    Kp += (size_t)64 * IN_DIM;
    Vp += 64;

#define HALF(CUR)                                                              \
    {                                                                          \
        *(bf16x8*)&KL[grp][CUR][kwoff] = kreg;                                 \
        *(bf16x8*)&VL[grp][CUR][vwoff] = vreg;                                 \
        kreg = *(const bf16x8*)Kp;                                             \
        vreg = *(const bf16x8*)Vp;                                             \
        Kp += (size_t)64 * IN_DIM;                                             \
        Vp += 64;                                                              \
        __syncthreads();                                                       \
        bf16x8 kf[4];                                                          \
        _Pragma("unroll")                                                      \
        for (int t = 0; t < 4; ++t)                                            \
            kf[t] = *(const bf16x8*)&KL[grp][CUR][kroff + t * 640];            \
        bf16x4 v0[4], v1[4];                                                   \
        _Pragma("unroll")                                                      \
        for (int t = 0; t < 4; ++t) {                                          \
            v0[t] = *(const bf16x4*)&VL[grp][CUR][vroff0 + t * 16];            \
            v1[t] = *(const bf16x4*)&VL[grp][CUR][vroff1 + t * 16];            \
        }                                                                      \
        f32x4 sa[4], sb[4];                                                    \
        __builtin_amdgcn_s_setprio(1);                                         \
        _Pragma("unroll")                                                      \
        for (int t = 0; t < 4; ++t) {                                          \
            sa[t] = __builtin_amdgcn_mfma_f32_16x16x32_bf16(kf[t], qfa, z, 0,0,0); \
            sb[t] = __builtin_amdgcn_mfma_f32_16x16x32_bf16(kf[t], qfb, z, 0,0,0); \
        }                                                                      \
        __builtin_amdgcn_s_setprio(0);                                         \
        _Pragma("unroll")                                                      \
        for (int tcp = 0; tcp < 2; ++tcp) {                                    \
            union { bf16x8 v; uint4 u; } pa, pb;                               \
            pa.u.x = packbf2(fast_exp2(sa[2*tcp][0]),   fast_exp2(sa[2*tcp][1]));   \
            pa.u.y = packbf2(fast_exp2(sa[2*tcp][2]),   fast_exp2(sa[2*tcp][3]));   \
            pa.u.z = packbf2(fast_exp2(sa[2*tcp+1][0]), fast_exp2(sa[2*tcp+1][1])); \
            pa.u.w = packbf2(fast_exp2(sa[2*tcp+1][2]), fast_exp2(sa[2*tcp+1][3])); \
            pb.u.x = packbf2(fast_exp2(sb[2*tcp][0]),   fast_exp2(sb[2*tcp][1]));   \
            pb.u.y = packbf2(fast_exp2(sb[2*tcp][2]),   fast_exp2(sb[2*tcp][3]));   \
            pb.u.z = packbf2(fast_exp2(sb[2*tcp+1][0]), fast_exp2(sb[2*tcp+1][1])); \
            pb.u.w = packbf2(fast_exp2(sb[2*tcp+1][2]), fast_exp2(sb[2*tcp+1][3])); \
            bfrag B0, B1;                                                      \
            B0.h[0] = v0[2*tcp]; B0.h[1] = v0[2*tcp+1];                        \
            B1.h[0] = v1[2*tcp]; B1.h[1] = v1[2*tcp+1];                        \
            __builtin_amdgcn_s_setprio(1);                                     \
            o0a = __builtin_amdgcn_mfma_f32_16x16x32_bf16(pa.v, B0.v, o0a, 0,0,0); \
            o1a = __builtin_amdgcn_mfma_f32_16x16x32_bf16(pa.v, B1.v, o1a, 0,0,0); \
            ola = __builtin_amdgcn_mfma_f32_16x16x32_bf16(pa.v, ones8, ola, 0,0,0); \
            o0b = __builtin_amdgcn_mfma_f32_16x16x32_bf16(pb.v, B0.v, o0b, 0,0,0); \
            o1b = __builtin_amdgcn_mfma_f32_16x16x32_bf16(pb.v, B1.v, o1b, 0,0,0); \
            olb = __builtin_amdgcn_mfma_f32_16x16x32_bf16(pb.v, ones8, olb, 0,0,0); \
            __builtin_amdgcn_s_setprio(0);                                     \
        }                                                                      \
    }

    for (int it = 0; it < NTOK / 256; ++it) {   // 16 iters x 128 kv per group
        HALF(0)
        HALF(1)
    }
#undef HALF

    // ---- combine the two kv-halves (pure sums), then epilogue by group 0
    if (grp) {
        float* d = &redC[wl][lane * 24];
        *(f32x4*)(d + 0)  = o0a;  *(f32x4*)(d + 4)  = o1a;  *(f32x4*)(d + 8)  = ola;
        *(f32x4*)(d + 12) = o0b;  *(f32x4*)(d + 16) = o1b;  *(f32x4*)(d + 20) = olb;
    }
    __syncthreads();
    if (!grp) {
        const float* s = &redC[wl][lane * 24];
        o0a += *(const f32x4*)(s + 0);
        o1a += *(const f32x4*)(s + 4);
        ola += *(const f32x4*)(s + 8);
        o0b += *(const f32x4*)(s + 12);
        o1b += *(const f32x4*)(s + 16);
        olb += *(const f32x4*)(s + 20);

        const float* tga = tgt + ((size_t)b * IN_DIM + h * HDIM + lc) * NTOK + qw + lg * 4;
        float4 r0a = *(const float4*)tga;
        float4 r1a = *(const float4*)(tga + (size_t)16 * NTOK);
        float4 r0b = *(const float4*)(tga + 16);
        float4 r1b = *(const float4*)(tga + (size_t)16 * NTOK + 16);

        bf16* opa = Wt + ((size_t)b * NTOK + qw + lg * 4) * IN_DIM + h * HDIM + lc;
        bf16* opb = opa + (size_t)16 * IN_DIM;
        #pragma unroll
        for (int r = 0; r < 4; ++r) {
            float inva = 1.f / ola[r];
            float invb = 1.f / olb[r];
            opa[(size_t)r * IN_DIM]      = __float2bfloat16(o0a[r] * inva + (&r0a.x)[r]);
            opa[(size_t)r * IN_DIM + 16] = __float2bfloat16(o1a[r] * inva + (&r1a.x)[r]);
            opb[(size_t)r * IN_DIM]      = __float2bfloat16(o0b[r] * invb + (&r0b.x)[r]);
            opb[(size_t)r * IN_DIM + 16] = __float2bfloat16(o1b[r] * invb + (&r1b.x)[r]);
        }
    }
}

// ---------------------------------------------------------------------------
// Kernel C: MFMA output projection.  out[b][n][d] = sum_c A[b][n][c]*Wo[d][c]
// ---------------------------------------------------------------------------
__global__ __launch_bounds__(256) void out_mfma(
    const bf16* __restrict__ A, const float* __restrict__ Wo,
    float* __restrict__ out)
{
    const int dh = blockIdx.y;
    const int b  = blockIdx.x >> 7;
    const int n0 = (blockIdx.x & 127) * 32;

    const int tid = threadIdx.x;
    const int wave = tid >> 6, lane = tid & 63;
    const int lg = lane >> 4, lc = lane & 15;
    const int wn = wave & 1, wdq = wave >> 1;

    __shared__ bf16 As[32 * 260];
    __shared__ bf16 Ws[2][128 * 36];

    {
        const bf16* Ab = A + ((size_t)b * NTOK + n0) * IN_DIM;
        for (int it = 0; it < 4; ++it) {
            int idx = it * 256 + tid;
            int r = idx >> 5, ch = idx & 31;
            bfrag v;
            v.v = *(const bf16x8*)(Ab + (size_t)r * IN_DIM + ch * 8);
            *(bf16x4*)&As[r * 260 + ch * 8]     = v.h[0];
            *(bf16x4*)&As[r * 260 + ch * 8 + 4] = v.h[1];
        }
    }
    const int wd = tid >> 1, wc = (tid & 1) * 16;
    const float* Wbase = Wo + (size_t)(dh * 128 + wd) * IN_DIM + wc;
    {
        float4 a = *(const float4*)(Wbase + 0);
        float4 bb = *(const float4*)(Wbase + 4);
        float4 cc = *(const float4*)(Wbase + 8);
        float4 dd = *(const float4*)(Wbase + 12);
        pack16(a, bb, cc, dd, &Ws[0][wd * 36 + wc]);
    }
    __syncthreads();

    f32x4 acc[4];
    #pragma unroll
    for (int t = 0; t < 4; ++t) acc[t] = f32x4{0.f, 0.f, 0.f, 0.f};

    for (int s = 0; s < 8; ++s) {
        const int c0 = s * 32;
        float4 pa, pb, pc, pd;
        if (s < 7) {
            const float* wn_ = Wbase + (s + 1) * 32;
            pa = *(const float4*)(wn_ + 0);
            pb = *(const float4*)(wn_ + 4);
            pc = *(const float4*)(wn_ + 8);
            pd = *(const float4*)(wn_ + 12);
        }
        bfrag af;
        const bf16* ap = &As[(wn * 16 + lc) * 260 + c0 + lg * 8];
        af.h[0] = *(const bf16x4*)ap;
        af.h[1] = *(const bf16x4*)(ap + 4);
        #pragma unroll
        for (int t = 0; t < 4; ++t) {
            bfrag wf;
            const bf16* wp = &Ws[s & 1][(wdq * 64 + t * 16 + lc) * 36 + lg * 8];
            wf.h[0] = *(const bf16x4*)wp;
            wf.h[1] = *(const bf16x4*)(wp + 4);
            acc[t] = __builtin_amdgcn_mfma_f32_16x16x32_bf16(af.v, wf.v, acc[t], 0, 0, 0);
        }
        if (s < 7) {
            __syncthreads();
            pack16(pa, pb, pc, pd, &Ws[(s + 1) & 1][wd * 36 + wc]);
            __syncthreads();
        }
    }

    const int nb = n0 + wn * 16 + lg * 4;
    #pragma unroll
    for (int t = 0; t < 4; ++t)
        #pragma unroll
        for (int r = 0; r < 4; ++r)
            out[((size_t)b * NTOK + nb + r) * IN_DIM + dh * 128 + wdq * 64 + t * 16 + lc]
                = acc[t][r];
}

// ---------------------------------------------------------------------------
extern "C" void kernel_launch(void* const* d_in, const int* in_sizes, int n_in,
                              void* d_out, int out_size, void* d_ws, size_t ws_size,
                              hipStream_t stream) {
    const float* tgt = (const float*)d_in[0];
    const float* src = (const float*)d_in[1];
    const float* Wq  = (const float*)d_in[2];
    const float* Wk  = (const float*)d_in[3];
    const float* Wv  = (const float*)d_in[4];
    const float* Wo  = (const float*)d_in[5];
    float* out = (float*)d_out;

    const size_t SZ = (size_t)BATCH * NTOK * IN_DIM * sizeof(bf16);  // 4 MiB
    char* w = (char*)d_ws;
    bf16* Qb  = (bf16*)(w);
    bf16* Kb  = (bf16*)(w + SZ);
    bf16* Vtb = (bf16*)(w + 2 * SZ);     // transposed V: [B][C][N]
    bf16* Wt  = (bf16*)(w + 3 * SZ);     // attn out + residual, [B][N][C]

    proj_mfma<<<dim3(256, 3, 2), 256, 0, stream>>>(tgt, src, Wq, Wk, Wv, Qb, Kb, Vtb);

    attn_mfma_kernel<<<512, 512, 0, stream>>>(Qb, Kb, Vtb, tgt, Wt);

    out_mfma<<<dim3(256, 2), 256, 0, stream>>>(Wt, Wo, out);
}